// Round 4
// baseline (301.981 us; speedup 1.0000x reference)
//
#include <hip/hip_runtime.h>
#include <cstdint>
#include <cstddef>

#define H 512
#define SEQ 128

typedef __bf16 v8bf __attribute__((ext_vector_type(8)));
typedef float v4f __attribute__((ext_vector_type(4)));
typedef unsigned short v8us __attribute__((ext_vector_type(8)));

__device__ __forceinline__ unsigned short f2bf(float f) {
    unsigned int u = __float_as_uint(f);
    u = (u + 0x7FFFu + ((u >> 16) & 1u)) >> 16;
    return (unsigned short)u;
}
__device__ __forceinline__ float bf2f(unsigned short h) {
    return __uint_as_float(((unsigned int)h) << 16);
}
__device__ __forceinline__ v8bf load_bf8(const unsigned short* p) {
    return *reinterpret_cast<const v8bf*>(p);
}
__device__ __forceinline__ float fast_tanh(float v) {
    float e = __expf(2.f * v);
    return 1.f - 2.f * __builtin_amdgcn_rcpf(e + 1.f);
}
__device__ __forceinline__ float fast_sigmoid(float v) {
    return __builtin_amdgcn_rcpf(1.f + __expf(-v));
}
// f32x8 -> bf16x8 via hardware cvt (RNE, same rounding as f2bf).
__device__ __forceinline__ v8bf cvt8(float4 lo, float4 hi) {
    v8bf r;
    r[0] = (__bf16)lo.x; r[1] = (__bf16)lo.y; r[2] = (__bf16)lo.z; r[3] = (__bf16)lo.w;
    r[4] = (__bf16)hi.x; r[5] = (__bf16)hi.y; r[6] = (__bf16)hi.z; r[7] = (__bf16)hi.w;
    return r;
}

// Swizzled B layout: frag[((c*16 + ks)*64 + lane)*8 + j] = W[g][k]
//   g = c*16 + (lane&15),  k = ks*32 + (lane>>4)*8 + j

// ---------------------------------------------------------------------------
// prep: build swizzled WyS (Wl[:, :512]), WiS (Wl[:, 512:]), WaS (Wa1^T)
// ---------------------------------------------------------------------------
__global__ __launch_bounds__(256) void prep_kernel(
        const float* __restrict__ Wa1, const float* __restrict__ Wl,
        unsigned short* __restrict__ WyS, unsigned short* __restrict__ WiS,
        unsigned short* __restrict__ WaS) {
    int tg = blockIdx.x * 256 + threadIdx.x;   // 0..98303
    int mat = tg >> 15;
    int idx = tg & 32767;
    int lane = idx & 63;
    int ks = (idx >> 6) & 15;
    int c = idx >> 10;
    int g = c * 16 + (lane & 15);
    int hb = ks * 32 + ((lane >> 4) << 3);
    unsigned short o[8];
    unsigned short* dst;
    if (mat == 0) {
        const float* s = Wl + (size_t)g * 1024 + hb;
#pragma unroll
        for (int j = 0; j < 8; ++j) o[j] = f2bf(s[j]);
        dst = WyS + (size_t)idx * 8;
    } else if (mat == 1) {
        const float* s = Wl + (size_t)g * 1024 + 512 + hb;
#pragma unroll
        for (int j = 0; j < 8; ++j) o[j] = f2bf(s[j]);
        dst = WiS + (size_t)idx * 8;
    } else {
#pragma unroll
        for (int j = 0; j < 8; ++j) o[j] = f2bf(Wa1[(size_t)(hb + j) * H + g]);
        dst = WaS + (size_t)idx * 8;
    }
    *reinterpret_cast<ushort4*>(dst)     = *reinterpret_cast<ushort4*>(&o[0]);
    *reinterpret_cast<ushort4*>(dst + 4) = *reinterpret_cast<ushort4*>(&o[4]);
}

// ---------------------------------------------------------------------------
// attn_pool: one block per (b, s<127).  wave = 32 rows x 128 cols, acc 2x8.
// (reverted to the pre-fusion form)
// ---------------------------------------------------------------------------
__global__ __launch_bounds__(256, 3) void attn_pool_kernel(
        const float* __restrict__ x, const unsigned short* __restrict__ WaS,
        const float* __restrict__ ba1, const float* __restrict__ wa2,
        float* __restrict__ ixf, unsigned short* __restrict__ ixb) {
    __shared__ __align__(16) unsigned short Xb[32][520];
    __shared__ float attn[32];
    __shared__ float scpart[4][32];

    int bid = blockIdx.x;
    int b = bid / 127, s = bid % 127;
    int t = threadIdx.x;

    const float4* x4 = reinterpret_cast<const float4*>(x + (size_t)(b * SEQ + s) * 32 * H);
#pragma unroll
    for (int i = 0; i < 16; ++i) {
        int idx4 = t + i * 256;
        float4 v = x4[idx4];
        int e = idx4 * 4, m = e >> 9, h = e & 511;
        ushort4 o;
        o.x = f2bf(v.x); o.y = f2bf(v.y); o.z = f2bf(v.z); o.w = f2bf(v.w);
        *reinterpret_cast<ushort4*>(&Xb[m][h]) = o;
    }
    __syncthreads();

    int w = t >> 6, lane = t & 63, q = lane >> 4, c16 = lane & 15;

    v4f acc[2][8];
#pragma unroll
    for (int mi = 0; mi < 2; ++mi)
#pragma unroll
        for (int ci = 0; ci < 8; ++ci) acc[mi][ci] = (v4f){0.f, 0.f, 0.f, 0.f};

    const unsigned short* Bb = WaS + (size_t)(w * 8 * 16) * 512 + lane * 8;

#pragma unroll
    for (int ks = 0; ks < 16; ++ks) {
        v8bf a0 = load_bf8(&Xb[c16][ks * 32 + q * 8]);
        v8bf a1 = load_bf8(&Xb[16 + c16][ks * 32 + q * 8]);
#pragma unroll
        for (int ci = 0; ci < 8; ++ci) {
            v8bf bb = load_bf8(Bb + (size_t)(ci * 16 + ks) * 512);
            acc[0][ci] = __builtin_amdgcn_mfma_f32_16x16x32_bf16(a0, bb, acc[0][ci], 0, 0, 0);
            acc[1][ci] = __builtin_amdgcn_mfma_f32_16x16x32_bf16(a1, bb, acc[1][ci], 0, 0, 0);
        }
    }

    float sr[2][4] = {{0.f, 0.f, 0.f, 0.f}, {0.f, 0.f, 0.f, 0.f}};
#pragma unroll
    for (int ci = 0; ci < 8; ++ci) {
        int g = (w * 8 + ci) * 16 + c16;
        float w2 = wa2[g];
        float bv = ba1[g];
#pragma unroll
        for (int mi = 0; mi < 2; ++mi)
#pragma unroll
            for (int i = 0; i < 4; ++i)
                sr[mi][i] += w2 * fast_tanh(acc[mi][ci][i] + bv);
    }
#pragma unroll
    for (int off = 1; off < 16; off <<= 1) {
#pragma unroll
        for (int mi = 0; mi < 2; ++mi)
#pragma unroll
            for (int i = 0; i < 4; ++i) sr[mi][i] += __shfl_xor(sr[mi][i], off);
    }
    if (c16 == 0) {
#pragma unroll
        for (int mi = 0; mi < 2; ++mi)
#pragma unroll
            for (int i = 0; i < 4; ++i) scpart[w][mi * 16 + q * 4 + i] = sr[mi][i];
    }
    __syncthreads();

    // wave-parallel softmax over the 32 scores.
    if (t < 64) {
        int m = t & 31;
        float v = scpart[0][m] + scpart[1][m] + scpart[2][m] + scpart[3][m];
        float mx = v;
#pragma unroll
        for (int off = 1; off < 32; off <<= 1) mx = fmaxf(mx, __shfl_xor(mx, off));
        float e = __expf(v - mx);
        float sum = e;
#pragma unroll
        for (int off = 1; off < 32; off <<= 1) sum += __shfl_xor(sum, off);
        if (t < 32) attn[m] = e * __builtin_amdgcn_rcpf(sum);
    }
    __syncthreads();

    int h0 = t * 2;
    float p0 = 0.f, p1 = 0.f;
#pragma unroll
    for (int m = 0; m < 32; ++m) {
        float am = attn[m];
        p0 += am * bf2f(Xb[m][h0]);
        p1 += am * bf2f(Xb[m][h0 + 1]);
    }
    size_t r = (size_t)bid;
    ixf[r * H + h0] = p0;
    ixf[r * H + h0 + 1] = p1;
    ixb[r * H + h0] = f2bf(p0);
    ixb[r * H + h0 + 1] = f2bf(p1);
}

// ---------------------------------------------------------------------------
// ipre: i_pre[r,g] = sum_h i_x[r,h] * Wi[g,h] + bl[g]   (r < 1016)
// ---------------------------------------------------------------------------
__global__ __launch_bounds__(256) void ipre_kernel(
        const unsigned short* __restrict__ ixb, const unsigned short* __restrict__ WiS,
        const float* __restrict__ bl, float* __restrict__ ipre) {
    int row16 = blockIdx.x * 16;
    int t = threadIdx.x, w = t >> 6, lane = t & 63, q = lane >> 4, c16 = lane & 15;
    int c0 = blockIdx.y * 8 + w * 2;

    v4f acc0 = {0.f, 0.f, 0.f, 0.f};
    v4f acc1 = {0.f, 0.f, 0.f, 0.f};
    const unsigned short* arow = ixb + (size_t)(row16 + c16) * H + q * 8;
#pragma unroll
    for (int ks = 0; ks < 16; ++ks) {
        v8bf a = load_bf8(arow + ks * 32);
        acc0 = __builtin_amdgcn_mfma_f32_16x16x32_bf16(
            a, load_bf8(WiS + (size_t)(c0 * 16 + ks) * 512 + lane * 8), acc0, 0, 0, 0);
        acc1 = __builtin_amdgcn_mfma_f32_16x16x32_bf16(
            a, load_bf8(WiS + (size_t)((c0 + 1) * 16 + ks) * 512 + lane * 8), acc1, 0, 0, 0);
    }
#pragma unroll
    for (int cc = 0; cc < 2; ++cc) {
        int g = (c0 + cc) * 16 + c16;
        float blv = bl[g];
        v4f a = cc ? acc1 : acc0;
#pragma unroll
        for (int i = 0; i < 4; ++i) {
            int row = row16 + q * 4 + i;
            if (row < 1016) ipre[(size_t)row * H + g] = a[i] + blv;
        }
    }
}

// ---------------------------------------------------------------------------
// main: out[b,0]=y[b,0]; s>=1: pre = y@Wy^T + i_pre, out = y + i_x*sigmoid(pre)
// NO LDS, NO barriers.  Each wave loads its A-fragments (contiguous 32B f32)
// straight from global y (tile is L2-resident across the block's 4 waves),
// converts f32->bf16 in-register (hardware cvt, RNE), MFMAs acc[4][8], and
// the epilogue re-reads y / ipre / ixf per-lane from L2.  Pure dataflow:
// the compiler can pipeline all 256 independent memory ops per thread.
// ---------------------------------------------------------------------------
__global__ __launch_bounds__(256) void main_kernel(
        const float* __restrict__ y, const unsigned short* __restrict__ WyS,
        const float* __restrict__ ixf, const float* __restrict__ ipre,
        float* __restrict__ out) {
    int s = blockIdx.x, b = blockIdx.y;
    int t = threadIdx.x;
    size_t base = (size_t)(b * SEQ + s) * 64 * H;

    if (s == 0) {
        const float4* y4 = reinterpret_cast<const float4*>(y + base);
        float4* o4 = reinterpret_cast<float4*>(out + base);
#pragma unroll
        for (int i = 0; i < 32; ++i) o4[t + i * 256] = y4[t + i * 256];
        return;
    }

    int r = b * 127 + (s - 1);
    int w = t >> 6, lane = t & 63, q = lane >> 4, c16 = lane & 15;

    // per-lane epilogue scalars (independent; issue early)
    float ipr[8], ixr[8];
#pragma unroll
    for (int ci = 0; ci < 8; ++ci) {
        int g = (w * 8 + ci) * 16 + c16;
        ipr[ci] = ipre[(size_t)r * H + g];
        ixr[ci] = ixf[(size_t)r * H + g];
    }

    v4f acc[4][8];
#pragma unroll
    for (int rt = 0; rt < 4; ++rt)
#pragma unroll
        for (int ci = 0; ci < 8; ++ci) acc[rt][ci] = (v4f){0.f, 0.f, 0.f, 0.f};

    const float* ytile = y + base;
    const unsigned short* Bb = WyS + (size_t)(w * 8 * 16) * 512 + lane * 8;

#pragma unroll
    for (int ks = 0; ks < 16; ++ks) {
        v8bf a[4];
#pragma unroll
        for (int rt = 0; rt < 4; ++rt) {
            const float* ap = ytile + (size_t)(rt * 16 + c16) * H + ks * 32 + q * 8;
            float4 lo = *reinterpret_cast<const float4*>(ap);
            float4 hi = *reinterpret_cast<const float4*>(ap + 4);
            a[rt] = cvt8(lo, hi);
        }
#pragma unroll
        for (int ci = 0; ci < 8; ++ci) {
            v8bf bb = load_bf8(Bb + (size_t)(ci * 16 + ks) * 512);
#pragma unroll
            for (int rt = 0; rt < 4; ++rt)
                acc[rt][ci] = __builtin_amdgcn_mfma_f32_16x16x32_bf16(
                    a[rt], bb, acc[rt][ci], 0, 0, 0);
        }
    }

#pragma unroll
    for (int ci = 0; ci < 8; ++ci) {
        int g = (w * 8 + ci) * 16 + c16;
        float ip = ipr[ci];
        float ixv = ixr[ci];
#pragma unroll
        for (int rt = 0; rt < 4; ++rt)
#pragma unroll
            for (int i = 0; i < 4; ++i) {
                int n = rt * 16 + q * 4 + i;
                float yv = ytile[(size_t)n * H + g];   // L2-hot residual
                float pre = acc[rt][ci][i] + ip;
                float gate = fast_sigmoid(pre);
                out[base + (size_t)n * H + g] = yv + ixv * gate;
            }
    }
}

// ---------------------------------------------------------------------------
extern "C" void kernel_launch(void* const* d_in, const int* in_sizes, int n_in,
                              void* d_out, int out_size, void* d_ws, size_t ws_size,
                              hipStream_t stream) {
    const float* x   = (const float*)d_in[0];
    const float* y   = (const float*)d_in[1];
    const float* Wa1 = (const float*)d_in[2];
    const float* ba1 = (const float*)d_in[3];
    const float* wa2 = (const float*)d_in[4];
    const float* Wl  = (const float*)d_in[5];
    const float* bl  = (const float*)d_in[6];
    float* out = (float*)d_out;

    char* ws = (char*)d_ws;
    unsigned short* WyS  = (unsigned short*)(ws);                     // 512 KB
    unsigned short* WiS  = (unsigned short*)(ws + 524288);            // 512 KB
    unsigned short* WaS  = (unsigned short*)(ws + 1048576);           // 512 KB
    float*          ixf  = (float*)(ws + 1572864);                    // 2 MB (1024 rows)
    unsigned short* ixb  = (unsigned short*)(ws + 3670016);           // 1 MB (1024 rows)
    float*          ipre = (float*)(ws + 4718592);                    // 2 MB (1024 rows)

    hipLaunchKernelGGL(prep_kernel, dim3(384), dim3(256), 0, stream, Wa1, Wl, WyS, WiS, WaS);
    hipLaunchKernelGGL(attn_pool_kernel, dim3(1016), dim3(256), 0, stream,
                       x, WaS, ba1, wa2, ixf, ixb);
    hipLaunchKernelGGL(ipre_kernel, dim3(64, 4), dim3(256), 0, stream, ixb, WiS, bl, ipre);
    hipLaunchKernelGGL(main_kernel, dim3(128, 8), dim3(256), 0, stream,
                       y, WyS, ixf, ipre, out);
}

// Round 6
// 205.710 us; speedup vs baseline: 1.4680x; 1.4680x over previous
//
#include <hip/hip_runtime.h>
#include <cstdint>
#include <cstddef>

#define H 512
#define SEQ 128

typedef __bf16 v8bf __attribute__((ext_vector_type(8)));
typedef float v4f __attribute__((ext_vector_type(4)));
typedef unsigned short v8us __attribute__((ext_vector_type(8)));

__device__ __forceinline__ unsigned short f2bf(float f) {
    unsigned int u = __float_as_uint(f);
    u = (u + 0x7FFFu + ((u >> 16) & 1u)) >> 16;
    return (unsigned short)u;
}
__device__ __forceinline__ float bf2f(unsigned short h) {
    return __uint_as_float(((unsigned int)h) << 16);
}
__device__ __forceinline__ v8bf load_bf8(const unsigned short* p) {
    return *reinterpret_cast<const v8bf*>(p);
}
__device__ __forceinline__ float fast_tanh(float v) {
    float e = __expf(2.f * v);
    return 1.f - 2.f * __builtin_amdgcn_rcpf(e + 1.f);
}
__device__ __forceinline__ float fast_sigmoid(float v) {
    return __builtin_amdgcn_rcpf(1.f + __expf(-v));
}

// Swizzled B layout: frag[((c*16 + ks)*64 + lane)*8 + j] = W[g][k]
//   g = c*16 + (lane&15),  k = ks*32 + (lane>>4)*8 + j

// ---------------------------------------------------------------------------
// prep: build swizzled WyS (Wl[:, :512]), WiS (Wl[:, 512:]), WaS (Wa1^T)
// ---------------------------------------------------------------------------
__global__ __launch_bounds__(256) void prep_kernel(
        const float* __restrict__ Wa1, const float* __restrict__ Wl,
        unsigned short* __restrict__ WyS, unsigned short* __restrict__ WiS,
        unsigned short* __restrict__ WaS) {
    int tg = blockIdx.x * 256 + threadIdx.x;   // 0..98303
    int mat = tg >> 15;
    int idx = tg & 32767;
    int lane = idx & 63;
    int ks = (idx >> 6) & 15;
    int c = idx >> 10;
    int g = c * 16 + (lane & 15);
    int hb = ks * 32 + ((lane >> 4) << 3);
    unsigned short o[8];
    unsigned short* dst;
    if (mat == 0) {
        const float* s = Wl + (size_t)g * 1024 + hb;
#pragma unroll
        for (int j = 0; j < 8; ++j) o[j] = f2bf(s[j]);
        dst = WyS + (size_t)idx * 8;
    } else if (mat == 1) {
        const float* s = Wl + (size_t)g * 1024 + 512 + hb;
#pragma unroll
        for (int j = 0; j < 8; ++j) o[j] = f2bf(s[j]);
        dst = WiS + (size_t)idx * 8;
    } else {
#pragma unroll
        for (int j = 0; j < 8; ++j) o[j] = f2bf(Wa1[(size_t)(hb + j) * H + g]);
        dst = WaS + (size_t)idx * 8;
    }
    *reinterpret_cast<ushort4*>(dst)     = *reinterpret_cast<ushort4*>(&o[0]);
    *reinterpret_cast<ushort4*>(dst + 4) = *reinterpret_cast<ushort4*>(&o[4]);
}

// ---------------------------------------------------------------------------
// conv: y (f32) -> yb (bf16), dedicated streaming kernel, fully coalesced.
// 33,554,432 floats = 8,388,608 float4-chunks; 2048 blocks x 256 thr x 16.
// ---------------------------------------------------------------------------
__global__ __launch_bounds__(256) void conv_kernel(
        const float* __restrict__ y, unsigned short* __restrict__ yb) {
    int tid = blockIdx.x * 256 + threadIdx.x;     // 0..524287
    const float4* y4 = reinterpret_cast<const float4*>(y);
    ushort4* o4 = reinterpret_cast<ushort4*>(yb);
#pragma unroll
    for (int j = 0; j < 16; ++j) {
        int c = tid + j * 524288;
        float4 v = y4[c];
        ushort4 o;
        o.x = f2bf(v.x); o.y = f2bf(v.y); o.z = f2bf(v.z); o.w = f2bf(v.w);
        o4[c] = o;
    }
}

// ---------------------------------------------------------------------------
// attn_pool: one block per (b, s<127).  wave = 32 rows x 128 cols, acc 2x8.
// launch_bounds(256,4): VGPR use is 72 (measured) <= 128 cap, LDS 34.3KB ->
// 4 blocks/CU (16 waves/CU) instead of 3.
// ---------------------------------------------------------------------------
__global__ __launch_bounds__(256, 4) void attn_pool_kernel(
        const float* __restrict__ x, const unsigned short* __restrict__ WaS,
        const float* __restrict__ ba1, const float* __restrict__ wa2,
        float* __restrict__ ixf, unsigned short* __restrict__ ixb) {
    __shared__ __align__(16) unsigned short Xb[32][520];
    __shared__ float attn[32];
    __shared__ float scpart[4][32];

    int bid = blockIdx.x;
    int b = bid / 127, s = bid % 127;
    int t = threadIdx.x;

    const float4* x4 = reinterpret_cast<const float4*>(x + (size_t)(b * SEQ + s) * 32 * H);
#pragma unroll
    for (int i = 0; i < 16; ++i) {
        int idx4 = t + i * 256;
        float4 v = x4[idx4];
        int e = idx4 * 4, m = e >> 9, h = e & 511;
        ushort4 o;
        o.x = f2bf(v.x); o.y = f2bf(v.y); o.z = f2bf(v.z); o.w = f2bf(v.w);
        *reinterpret_cast<ushort4*>(&Xb[m][h]) = o;
    }
    __syncthreads();

    int w = t >> 6, lane = t & 63, q = lane >> 4, c16 = lane & 15;

    v4f acc[2][8];
#pragma unroll
    for (int mi = 0; mi < 2; ++mi)
#pragma unroll
        for (int ci = 0; ci < 8; ++ci) acc[mi][ci] = (v4f){0.f, 0.f, 0.f, 0.f};

    const unsigned short* Bb = WaS + (size_t)(w * 8 * 16) * 512 + lane * 8;

#pragma unroll
    for (int ks = 0; ks < 16; ++ks) {
        v8bf a0 = load_bf8(&Xb[c16][ks * 32 + q * 8]);
        v8bf a1 = load_bf8(&Xb[16 + c16][ks * 32 + q * 8]);
#pragma unroll
        for (int ci = 0; ci < 8; ++ci) {
            v8bf bb = load_bf8(Bb + (size_t)(ci * 16 + ks) * 512);
            acc[0][ci] = __builtin_amdgcn_mfma_f32_16x16x32_bf16(a0, bb, acc[0][ci], 0, 0, 0);
            acc[1][ci] = __builtin_amdgcn_mfma_f32_16x16x32_bf16(a1, bb, acc[1][ci], 0, 0, 0);
        }
    }

    float sr[2][4] = {{0.f, 0.f, 0.f, 0.f}, {0.f, 0.f, 0.f, 0.f}};
#pragma unroll
    for (int ci = 0; ci < 8; ++ci) {
        int g = (w * 8 + ci) * 16 + c16;
        float w2 = wa2[g];
        float bv = ba1[g];
#pragma unroll
        for (int mi = 0; mi < 2; ++mi)
#pragma unroll
            for (int i = 0; i < 4; ++i)
                sr[mi][i] += w2 * fast_tanh(acc[mi][ci][i] + bv);
    }
#pragma unroll
    for (int off = 1; off < 16; off <<= 1) {
#pragma unroll
        for (int mi = 0; mi < 2; ++mi)
#pragma unroll
            for (int i = 0; i < 4; ++i) sr[mi][i] += __shfl_xor(sr[mi][i], off);
    }
    if (c16 == 0) {
#pragma unroll
        for (int mi = 0; mi < 2; ++mi)
#pragma unroll
            for (int i = 0; i < 4; ++i) scpart[w][mi * 16 + q * 4 + i] = sr[mi][i];
    }
    __syncthreads();

    // wave-parallel softmax over the 32 scores.
    if (t < 64) {
        int m = t & 31;
        float v = scpart[0][m] + scpart[1][m] + scpart[2][m] + scpart[3][m];
        float mx = v;
#pragma unroll
        for (int off = 1; off < 32; off <<= 1) mx = fmaxf(mx, __shfl_xor(mx, off));
        float e = __expf(v - mx);
        float sum = e;
#pragma unroll
        for (int off = 1; off < 32; off <<= 1) sum += __shfl_xor(sum, off);
        if (t < 32) attn[m] = e * __builtin_amdgcn_rcpf(sum);
    }
    __syncthreads();

    int h0 = t * 2;
    float p0 = 0.f, p1 = 0.f;
#pragma unroll
    for (int m = 0; m < 32; ++m) {
        float am = attn[m];
        p0 += am * bf2f(Xb[m][h0]);
        p1 += am * bf2f(Xb[m][h0 + 1]);
    }
    size_t r = (size_t)bid;
    ixf[r * H + h0] = p0;
    ixf[r * H + h0 + 1] = p1;
    ixb[r * H + h0] = f2bf(p0);
    ixb[r * H + h0 + 1] = f2bf(p1);
}

// ---------------------------------------------------------------------------
// ipre: i_pre[r,g] = sum_h i_x[r,h] * Wi[g,h] + bl[g]   (r < 1016)
// ---------------------------------------------------------------------------
__global__ __launch_bounds__(256) void ipre_kernel(
        const unsigned short* __restrict__ ixb, const unsigned short* __restrict__ WiS,
        const float* __restrict__ bl, float* __restrict__ ipre) {
    int row16 = blockIdx.x * 16;
    int t = threadIdx.x, w = t >> 6, lane = t & 63, q = lane >> 4, c16 = lane & 15;
    int c0 = blockIdx.y * 8 + w * 2;

    v4f acc0 = {0.f, 0.f, 0.f, 0.f};
    v4f acc1 = {0.f, 0.f, 0.f, 0.f};
    const unsigned short* arow = ixb + (size_t)(row16 + c16) * H + q * 8;
#pragma unroll
    for (int ks = 0; ks < 16; ++ks) {
        v8bf a = load_bf8(arow + ks * 32);
        acc0 = __builtin_amdgcn_mfma_f32_16x16x32_bf16(
            a, load_bf8(WiS + (size_t)(c0 * 16 + ks) * 512 + lane * 8), acc0, 0, 0, 0);
        acc1 = __builtin_amdgcn_mfma_f32_16x16x32_bf16(
            a, load_bf8(WiS + (size_t)((c0 + 1) * 16 + ks) * 512 + lane * 8), acc1, 0, 0, 0);
    }
#pragma unroll
    for (int cc = 0; cc < 2; ++cc) {
        int g = (c0 + cc) * 16 + c16;
        float blv = bl[g];
        v4f a = cc ? acc1 : acc0;
#pragma unroll
        for (int i = 0; i < 4; ++i) {
            int row = row16 + q * 4 + i;
            if (row < 1016) ipre[(size_t)row * H + g] = a[i] + blv;
        }
    }
}

// ---------------------------------------------------------------------------
// main: out[b,0]=y[b,0]; s>=1: pre = y@Wy^T + i_pre, out = y + i_x*sigmoid(pre)
// One block per (b, s, half): 32 rows x 512 cols from PRE-CONVERTED bf16 yb.
// Staging: 8 x ushort8 loads + 8 x ds_write_b128 per thread (no f32 convert).
// LDS 37.4 KB; launch_bounds(256,3); acc[2][8]=64 AGPR -> 3 blocks/CU.
// (This is the round-3 main, measured ~70us by subtraction.)
// ---------------------------------------------------------------------------
__global__ __launch_bounds__(256, 3) void main_kernel(
        const float* __restrict__ y, const unsigned short* __restrict__ yb,
        const unsigned short* __restrict__ WyS,
        const float* __restrict__ ixf, const float* __restrict__ ipre,
        float* __restrict__ out) {
    int half = blockIdx.x & 1;
    int s = blockIdx.x >> 1;           // 0..127
    int b = blockIdx.y;
    int t = threadIdx.x;
    size_t base  = (size_t)(b * SEQ + s) * 64 * H;
    size_t rbase = base + (size_t)half * 32 * H;   // this half's 32 rows

    if (s == 0) {
        const float4* y4 = reinterpret_cast<const float4*>(y + rbase);
        float4* o4 = reinterpret_cast<float4*>(out + rbase);
#pragma unroll
        for (int i = 0; i < 16; ++i) o4[t + i * 256] = y4[t + i * 256];
        return;
    }

    __shared__ __align__(16) unsigned short Yb[32][520];
    __shared__ float ip_s[512];
    __shared__ float ix_s[512];

    int r = b * 127 + (s - 1);
    const unsigned short* ybp = yb + rbase;

    // stage 32 rows x 512 cols bf16: 2048 16B-chunks / 256 threads = 8 each.
#pragma unroll
    for (int j = 0; j < 8; ++j) {
        int idx8 = t + j * 256;            // 0..2047
        int row = idx8 >> 6;               // 64 chunks per row
        int ck  = idx8 & 63;
        v8us v = *reinterpret_cast<const v8us*>(ybp + (size_t)row * H + ck * 8);
        *reinterpret_cast<v8us*>(&Yb[row][ck * 8]) = v;
    }
    ip_s[t]       = ipre[(size_t)r * H + t];
    ip_s[t + 256] = ipre[(size_t)r * H + t + 256];
    ix_s[t]       = ixf[(size_t)r * H + t];
    ix_s[t + 256] = ixf[(size_t)r * H + t + 256];
    __syncthreads();

    int w = t >> 6, lane = t & 63, q = lane >> 4, c16 = lane & 15;

    v4f acc[2][8];
#pragma unroll
    for (int rt = 0; rt < 2; ++rt)
#pragma unroll
        for (int ci = 0; ci < 8; ++ci) acc[rt][ci] = (v4f){0.f, 0.f, 0.f, 0.f};

    const unsigned short* Bb = WyS + (size_t)(w * 8 * 16) * 512 + lane * 8;

#pragma unroll
    for (int ks = 0; ks < 16; ++ks) {
        v8bf a0 = load_bf8(&Yb[c16][ks * 32 + q * 8]);
        v8bf a1 = load_bf8(&Yb[16 + c16][ks * 32 + q * 8]);
#pragma unroll
        for (int ci = 0; ci < 8; ++ci) {
            v8bf bb = load_bf8(Bb + (size_t)(ci * 16 + ks) * 512);
            acc[0][ci] = __builtin_amdgcn_mfma_f32_16x16x32_bf16(a0, bb, acc[0][ci], 0, 0, 0);
            acc[1][ci] = __builtin_amdgcn_mfma_f32_16x16x32_bf16(a1, bb, acc[1][ci], 0, 0, 0);
        }
    }

#pragma unroll
    for (int ci = 0; ci < 8; ++ci) {
        int g = (w * 8 + ci) * 16 + c16;
        float ip = ip_s[g];
        float ixv = ix_s[g];
#pragma unroll
        for (int rt = 0; rt < 2; ++rt)
#pragma unroll
            for (int i = 0; i < 4; ++i) {
                int nl = rt * 16 + q * 4 + i;      // local row 0..31
                float pre = acc[rt][ci][i] + ip;
                float gate = fast_sigmoid(pre);
                out[rbase + (size_t)nl * H + g] = bf2f(Yb[nl][g]) + ixv * gate;
            }
    }
}

// ---------------------------------------------------------------------------
extern "C" void kernel_launch(void* const* d_in, const int* in_sizes, int n_in,
                              void* d_out, int out_size, void* d_ws, size_t ws_size,
                              hipStream_t stream) {
    const float* x   = (const float*)d_in[0];
    const float* y   = (const float*)d_in[1];
    const float* Wa1 = (const float*)d_in[2];
    const float* ba1 = (const float*)d_in[3];
    const float* wa2 = (const float*)d_in[4];
    const float* Wl  = (const float*)d_in[5];
    const float* bl  = (const float*)d_in[6];
    float* out = (float*)d_out;

    char* ws = (char*)d_ws;
    unsigned short* WyS  = (unsigned short*)(ws);                     // 512 KB
    unsigned short* WiS  = (unsigned short*)(ws + 524288);            // 512 KB
    unsigned short* WaS  = (unsigned short*)(ws + 1048576);           // 512 KB
    float*          ixf  = (float*)(ws + 1572864);                    // 2 MB (1024 rows)
    unsigned short* ixb  = (unsigned short*)(ws + 3670016);           // 1 MB (1024 rows)
    float*          ipre = (float*)(ws + 4718592);                    // 2 MB (1024 rows)
    unsigned short* yb   = (unsigned short*)(ws + 6815744);           // 64 MB (bf16 y)

    hipLaunchKernelGGL(prep_kernel, dim3(384), dim3(256), 0, stream, Wa1, Wl, WyS, WiS, WaS);
    hipLaunchKernelGGL(attn_pool_kernel, dim3(1016), dim3(256), 0, stream,
                       x, WaS, ba1, wa2, ixf, ixb);
    hipLaunchKernelGGL(ipre_kernel, dim3(64, 4), dim3(256), 0, stream, ixb, WiS, bl, ipre);
    // conv right before main: y read here makes y/yb L3-hot for main.
    hipLaunchKernelGGL(conv_kernel, dim3(2048), dim3(256), 0, stream, y, yb);
    hipLaunchKernelGGL(main_kernel, dim3(256, 8), dim3(256), 0, stream,
                       y, yb, WyS, ixf, ipre, out);
}

// Round 7
// 165.752 us; speedup vs baseline: 1.8219x; 1.2411x over previous
//
#include <hip/hip_runtime.h>
#include <cstdint>
#include <cstddef>

#define H 512
#define SEQ 128

typedef __bf16 v8bf __attribute__((ext_vector_type(8)));
typedef float v4f __attribute__((ext_vector_type(4)));
typedef unsigned short v8us __attribute__((ext_vector_type(8)));

__device__ __forceinline__ unsigned short f2bf(float f) {
    unsigned int u = __float_as_uint(f);
    u = (u + 0x7FFFu + ((u >> 16) & 1u)) >> 16;
    return (unsigned short)u;
}
__device__ __forceinline__ float bf2f(unsigned short h) {
    return __uint_as_float(((unsigned int)h) << 16);
}
__device__ __forceinline__ v8bf load_bf8(const unsigned short* p) {
    return *reinterpret_cast<const v8bf*>(p);
}
__device__ __forceinline__ float fast_tanh(float v) {
    float e = __expf(2.f * v);
    return 1.f - 2.f * __builtin_amdgcn_rcpf(e + 1.f);
}
__device__ __forceinline__ float fast_sigmoid(float v) {
    return __builtin_amdgcn_rcpf(1.f + __expf(-v));
}
__device__ __forceinline__ v8us cvt8u(float4 lo, float4 hi) {
    v8us r;
    r[0] = f2bf(lo.x); r[1] = f2bf(lo.y); r[2] = f2bf(lo.z); r[3] = f2bf(lo.w);
    r[4] = f2bf(hi.x); r[5] = f2bf(hi.y); r[6] = f2bf(hi.z); r[7] = f2bf(hi.w);
    return r;
}

// Swizzled B layout: frag[((c*16 + ks)*64 + lane)*8 + j] = W[g][k]
//   g = c*16 + (lane&15),  k = ks*32 + (lane>>4)*8 + j

// ---------------------------------------------------------------------------
// prep: build swizzled WyS (Wl[:, :512]), WiS (Wl[:, 512:]), WaS (Wa1^T)
// ---------------------------------------------------------------------------
__global__ __launch_bounds__(256) void prep_kernel(
        const float* __restrict__ Wa1, const float* __restrict__ Wl,
        unsigned short* __restrict__ WyS, unsigned short* __restrict__ WiS,
        unsigned short* __restrict__ WaS) {
    int tg = blockIdx.x * 256 + threadIdx.x;   // 0..98303
    int mat = tg >> 15;
    int idx = tg & 32767;
    int lane = idx & 63;
    int ks = (idx >> 6) & 15;
    int c = idx >> 10;
    int g = c * 16 + (lane & 15);
    int hb = ks * 32 + ((lane >> 4) << 3);
    unsigned short o[8];
    unsigned short* dst;
    if (mat == 0) {
        const float* s = Wl + (size_t)g * 1024 + hb;
#pragma unroll
        for (int j = 0; j < 8; ++j) o[j] = f2bf(s[j]);
        dst = WyS + (size_t)idx * 8;
    } else if (mat == 1) {
        const float* s = Wl + (size_t)g * 1024 + 512 + hb;
#pragma unroll
        for (int j = 0; j < 8; ++j) o[j] = f2bf(s[j]);
        dst = WiS + (size_t)idx * 8;
    } else {
#pragma unroll
        for (int j = 0; j < 8; ++j) o[j] = f2bf(Wa1[(size_t)(hb + j) * H + g]);
        dst = WaS + (size_t)idx * 8;
    }
    *reinterpret_cast<ushort4*>(dst)     = *reinterpret_cast<ushort4*>(&o[0]);
    *reinterpret_cast<ushort4*>(dst + 4) = *reinterpret_cast<ushort4*>(&o[4]);
}

// ---------------------------------------------------------------------------
// attn_pool: one block per (b, s<127).  wave = 32 rows x 128 cols, acc 2x8.
// ---------------------------------------------------------------------------
__global__ __launch_bounds__(256, 4) void attn_pool_kernel(
        const float* __restrict__ x, const unsigned short* __restrict__ WaS,
        const float* __restrict__ ba1, const float* __restrict__ wa2,
        float* __restrict__ ixf, unsigned short* __restrict__ ixb) {
    __shared__ __align__(16) unsigned short Xb[32][520];
    __shared__ float attn[32];
    __shared__ float scpart[4][32];

    int bid = blockIdx.x;
    int b = bid / 127, s = bid % 127;
    int t = threadIdx.x;

    const float4* x4 = reinterpret_cast<const float4*>(x + (size_t)(b * SEQ + s) * 32 * H);
#pragma unroll
    for (int i = 0; i < 16; ++i) {
        int idx4 = t + i * 256;
        float4 v = x4[idx4];
        int e = idx4 * 4, m = e >> 9, h = e & 511;
        ushort4 o;
        o.x = f2bf(v.x); o.y = f2bf(v.y); o.z = f2bf(v.z); o.w = f2bf(v.w);
        *reinterpret_cast<ushort4*>(&Xb[m][h]) = o;
    }
    __syncthreads();

    int w = t >> 6, lane = t & 63, q = lane >> 4, c16 = lane & 15;

    v4f acc[2][8];
#pragma unroll
    for (int mi = 0; mi < 2; ++mi)
#pragma unroll
        for (int ci = 0; ci < 8; ++ci) acc[mi][ci] = (v4f){0.f, 0.f, 0.f, 0.f};

    const unsigned short* Bb = WaS + (size_t)(w * 8 * 16) * 512 + lane * 8;

#pragma unroll
    for (int ks = 0; ks < 16; ++ks) {
        v8bf a0 = load_bf8(&Xb[c16][ks * 32 + q * 8]);
        v8bf a1 = load_bf8(&Xb[16 + c16][ks * 32 + q * 8]);
#pragma unroll
        for (int ci = 0; ci < 8; ++ci) {
            v8bf bb = load_bf8(Bb + (size_t)(ci * 16 + ks) * 512);
            acc[0][ci] = __builtin_amdgcn_mfma_f32_16x16x32_bf16(a0, bb, acc[0][ci], 0, 0, 0);
            acc[1][ci] = __builtin_amdgcn_mfma_f32_16x16x32_bf16(a1, bb, acc[1][ci], 0, 0, 0);
        }
    }

    float sr[2][4] = {{0.f, 0.f, 0.f, 0.f}, {0.f, 0.f, 0.f, 0.f}};
#pragma unroll
    for (int ci = 0; ci < 8; ++ci) {
        int g = (w * 8 + ci) * 16 + c16;
        float w2 = wa2[g];
        float bv = ba1[g];
#pragma unroll
        for (int mi = 0; mi < 2; ++mi)
#pragma unroll
            for (int i = 0; i < 4; ++i)
                sr[mi][i] += w2 * fast_tanh(acc[mi][ci][i] + bv);
    }
#pragma unroll
    for (int off = 1; off < 16; off <<= 1) {
#pragma unroll
        for (int mi = 0; mi < 2; ++mi)
#pragma unroll
            for (int i = 0; i < 4; ++i) sr[mi][i] += __shfl_xor(sr[mi][i], off);
    }
    if (c16 == 0) {
#pragma unroll
        for (int mi = 0; mi < 2; ++mi)
#pragma unroll
            for (int i = 0; i < 4; ++i) scpart[w][mi * 16 + q * 4 + i] = sr[mi][i];
    }
    __syncthreads();

    if (t < 64) {
        int m = t & 31;
        float v = scpart[0][m] + scpart[1][m] + scpart[2][m] + scpart[3][m];
        float mx = v;
#pragma unroll
        for (int off = 1; off < 32; off <<= 1) mx = fmaxf(mx, __shfl_xor(mx, off));
        float e = __expf(v - mx);
        float sum = e;
#pragma unroll
        for (int off = 1; off < 32; off <<= 1) sum += __shfl_xor(sum, off);
        if (t < 32) attn[m] = e * __builtin_amdgcn_rcpf(sum);
    }
    __syncthreads();

    int h0 = t * 2;
    float p0 = 0.f, p1 = 0.f;
#pragma unroll
    for (int m = 0; m < 32; ++m) {
        float am = attn[m];
        p0 += am * bf2f(Xb[m][h0]);
        p1 += am * bf2f(Xb[m][h0 + 1]);
    }
    size_t r = (size_t)bid;
    ixf[r * H + h0] = p0;
    ixf[r * H + h0 + 1] = p1;
    ixb[r * H + h0] = f2bf(p0);
    ixb[r * H + h0 + 1] = f2bf(p1);
}

// ---------------------------------------------------------------------------
// ipre: i_pre[r,g] = sum_h i_x[r,h] * Wi[g,h] + bl[g]   (r < 1016)
// ---------------------------------------------------------------------------
__global__ __launch_bounds__(256) void ipre_kernel(
        const unsigned short* __restrict__ ixb, const unsigned short* __restrict__ WiS,
        const float* __restrict__ bl, float* __restrict__ ipre) {
    int row16 = blockIdx.x * 16;
    int t = threadIdx.x, w = t >> 6, lane = t & 63, q = lane >> 4, c16 = lane & 15;
    int c0 = blockIdx.y * 8 + w * 2;

    v4f acc0 = {0.f, 0.f, 0.f, 0.f};
    v4f acc1 = {0.f, 0.f, 0.f, 0.f};
    const unsigned short* arow = ixb + (size_t)(row16 + c16) * H + q * 8;
#pragma unroll
    for (int ks = 0; ks < 16; ++ks) {
        v8bf a = load_bf8(arow + ks * 32);
        acc0 = __builtin_amdgcn_mfma_f32_16x16x32_bf16(
            a, load_bf8(WiS + (size_t)(c0 * 16 + ks) * 512 + lane * 8), acc0, 0, 0, 0);
        acc1 = __builtin_amdgcn_mfma_f32_16x16x32_bf16(
            a, load_bf8(WiS + (size_t)((c0 + 1) * 16 + ks) * 512 + lane * 8), acc1, 0, 0, 0);
    }
#pragma unroll
    for (int cc = 0; cc < 2; ++cc) {
        int g = (c0 + cc) * 16 + c16;
        float blv = bl[g];
        v4f a = cc ? acc1 : acc0;
#pragma unroll
        for (int i = 0; i < 4; ++i) {
            int row = row16 + q * 4 + i;
            if (row < 1016) ipre[(size_t)row * H + g] = a[i] + blv;
        }
    }
}

// ---------------------------------------------------------------------------
// main v7: block-tiled GEMM, B staged through LDS (reused by whole block).
// Block = 128 rows x 256 cols; 512 thr = 8 waves (4 row-groups x 2 col-halves),
// wave = 32x128, acc[2][8] = 64 AGPR.  K in 16 phases of BK=32, double-buffered
// LDS (A 128x32 bf16 converted from f32, B 16 col-groups x 1KB), T14 pattern:
// phase p+1 loads issued before compute(p), written after, one barrier/phase.
// B traffic drops 1.05 GB -> 260 MB (was the L3-BW wall at ~9.3 TB/s).
// LDS 56 KB; launch_bounds(512,4) -> target 2 blocks/CU (16 waves).
// ---------------------------------------------------------------------------
__global__ __launch_bounds__(512, 4) void main_kernel(
        const float* __restrict__ y, const unsigned short* __restrict__ WyS,
        const float* __restrict__ ixf, const float* __restrict__ ipre,
        float* __restrict__ out) {
    int bid = blockIdx.x;
    int t = threadIdx.x;

    if (bid >= 1016) {
        // s==0 passthrough: 16 blocks, each copies 32 rows x 512 cols f32.
        int cb = bid - 1016;             // 0..15
        int b = cb >> 1, half = cb & 1;
        size_t base = ((size_t)(b * SEQ)) * 64 * H + (size_t)half * 32 * H;
        const float4* y4 = reinterpret_cast<const float4*>(y + base);
        float4* o4 = reinterpret_cast<float4*>(out + base);
#pragma unroll
        for (int i = 0; i < 8; ++i) o4[t + i * 512] = y4[t + i * 512];
        return;
    }

    int rg = bid >> 1;                   // row-group: 128 rows = tiles 2rg, 2rg+1
    int ch = bid & 1;                    // col half: g in [ch*256, ch*256+256)

    __shared__ __align__(16) unsigned short Ab[2][128 * 40];   // 40 = 32 + 8 pad
    __shared__ __align__(16) unsigned short Bb[2][16 * 512];
    __shared__ float ip_s[2][256];
    __shared__ float ix_s[2][256];

    int t0 = rg * 2;

    // ---- per-thread A staging assignment (fixed row, 8 f32 per phase) ----
    int arow  = t >> 2;                  // 0..127
    int acol0 = (t & 3) * 8;             // 0,8,16,24
    int atid  = t0 + (arow >> 6);
    int ab    = atid / 127, asm1 = atid % 127;
    const float* yrow = y + ((size_t)(ab * SEQ + asm1 + 1) * 64 + (arow & 63)) * H;

    // ---- per-thread B staging assignment (2 chunks of 16B per phase) ----
    int w = t >> 6, lane = t & 63, q = lane >> 4, c16 = lane & 15;
    int ck0 = w * 2;                     // chunks ck0, ck0+1 (0..15)
    const unsigned short* bsrc0 = WyS + (size_t)((ch * 16 + ck0) * 16) * 512 + lane * 8;
    const unsigned short* bsrc1 = WyS + (size_t)((ch * 16 + ck0 + 1) * 16) * 512 + lane * 8;

    // ---- ip/ix staging (once) ----
    {
        int tile = t >> 8, gl = t & 255;
        size_t rrow = (size_t)(t0 + tile) * H + ch * 256 + gl;
        ip_s[tile][gl] = ipre[rrow];
        ix_s[tile][gl] = ixf[rrow];
    }

    // ---- prologue: stage phase 0 ----
    {
        float4 a0 = *reinterpret_cast<const float4*>(yrow + acol0);
        float4 a1 = *reinterpret_cast<const float4*>(yrow + acol0 + 4);
        v8us b0 = *reinterpret_cast<const v8us*>(bsrc0);
        v8us b1 = *reinterpret_cast<const v8us*>(bsrc1);
        *reinterpret_cast<v8us*>(&Ab[0][arow * 40 + acol0]) = cvt8u(a0, a1);
        *reinterpret_cast<v8us*>(&Bb[0][ck0 * 512 + lane * 8]) = b0;
        *reinterpret_cast<v8us*>(&Bb[0][(ck0 + 1) * 512 + lane * 8]) = b1;
    }
    __syncthreads();

    int wr = w >> 1;                     // 0..3  row-group within block
    int wc = w & 1;                      // 0..1  col-half within block's 256

    v4f acc[2][8];
#pragma unroll
    for (int rt = 0; rt < 2; ++rt)
#pragma unroll
        for (int ci = 0; ci < 8; ++ci) acc[rt][ci] = (v4f){0.f, 0.f, 0.f, 0.f};

    // ---- main K loop: 16 phases, dbuf, issue-early / write-late ----
#pragma unroll
    for (int p = 0; p < 16; ++p) {
        const int cur = p & 1;
        float4 na0, na1; v8us nb0, nb1;
        if (p < 15) {
            na0 = *reinterpret_cast<const float4*>(yrow + (p + 1) * 32 + acol0);
            na1 = *reinterpret_cast<const float4*>(yrow + (p + 1) * 32 + acol0 + 4);
            nb0 = *reinterpret_cast<const v8us*>(bsrc0 + (p + 1) * 512);
            nb1 = *reinterpret_cast<const v8us*>(bsrc1 + (p + 1) * 512);
        }

        v8bf af0 = load_bf8(&Ab[cur][(wr * 32 + c16) * 40 + q * 8]);
        v8bf af1 = load_bf8(&Ab[cur][(wr * 32 + 16 + c16) * 40 + q * 8]);
#pragma unroll
        for (int ci = 0; ci < 8; ++ci) {
            v8bf bf = load_bf8(&Bb[cur][(wc * 8 + ci) * 512 + lane * 8]);
            acc[0][ci] = __builtin_amdgcn_mfma_f32_16x16x32_bf16(af0, bf, acc[0][ci], 0, 0, 0);
            acc[1][ci] = __builtin_amdgcn_mfma_f32_16x16x32_bf16(af1, bf, acc[1][ci], 0, 0, 0);
        }

        if (p < 15) {
            *reinterpret_cast<v8us*>(&Ab[cur ^ 1][arow * 40 + acol0]) = cvt8u(na0, na1);
            *reinterpret_cast<v8us*>(&Bb[cur ^ 1][ck0 * 512 + lane * 8]) = nb0;
            *reinterpret_cast<v8us*>(&Bb[cur ^ 1][(ck0 + 1) * 512 + lane * 8]) = nb1;
            __syncthreads();
        }
    }

    // ---- epilogue: out = y + ix * sigmoid(acc + ip), f32 residual ----
    int tb0 = t0, tb1 = t0 + 1;
    size_t obase0 = ((size_t)((tb0 / 127) * SEQ + tb0 % 127 + 1) * 64) * H;
    size_t obase1 = ((size_t)((tb1 / 127) * SEQ + tb1 % 127 + 1) * 64) * H;
    int tile = wr >> 1;                  // wave-uniform: rows 0..63 -> tile 0
    size_t obase = tile ? obase1 : obase0;

#pragma unroll
    for (int ci = 0; ci < 8; ++ci) {
        int gl = (wc * 8 + ci) * 16 + c16;       // 0..255
        int g = ch * 256 + gl;
        float ip = ip_s[tile][gl];
        float ixv = ix_s[tile][gl];
#pragma unroll
        for (int rt = 0; rt < 2; ++rt) {
#pragma unroll
            for (int i = 0; i < 4; ++i) {
                int n = ((wr & 1) * 32) + rt * 16 + q * 4 + i;   // row within tile
                size_t off = obase + (size_t)n * H + g;
                float yv = y[off];
                float pre = acc[rt][ci][i] + ip;
                out[off] = yv + ixv * fast_sigmoid(pre);
            }
        }
    }
}

// ---------------------------------------------------------------------------
extern "C" void kernel_launch(void* const* d_in, const int* in_sizes, int n_in,
                              void* d_out, int out_size, void* d_ws, size_t ws_size,
                              hipStream_t stream) {
    const float* x   = (const float*)d_in[0];
    const float* y   = (const float*)d_in[1];
    const float* Wa1 = (const float*)d_in[2];
    const float* ba1 = (const float*)d_in[3];
    const float* wa2 = (const float*)d_in[4];
    const float* Wl  = (const float*)d_in[5];
    const float* bl  = (const float*)d_in[6];
    float* out = (float*)d_out;

    char* ws = (char*)d_ws;
    unsigned short* WyS  = (unsigned short*)(ws);                     // 512 KB
    unsigned short* WiS  = (unsigned short*)(ws + 524288);            // 512 KB
    unsigned short* WaS  = (unsigned short*)(ws + 1048576);           // 512 KB
    float*          ixf  = (float*)(ws + 1572864);                    // 2 MB (1024 rows)
    unsigned short* ixb  = (unsigned short*)(ws + 3670016);           // 1 MB (1024 rows)
    float*          ipre = (float*)(ws + 4718592);                    // 2 MB (1024 rows)

    hipLaunchKernelGGL(prep_kernel, dim3(384), dim3(256), 0, stream, Wa1, Wl, WyS, WiS, WaS);
    hipLaunchKernelGGL(attn_pool_kernel, dim3(1016), dim3(256), 0, stream,
                       x, WaS, ba1, wa2, ixf, ixb);
    hipLaunchKernelGGL(ipre_kernel, dim3(64, 4), dim3(256), 0, stream, ixb, WiS, bl, ipre);
    hipLaunchKernelGGL(main_kernel, dim3(1032), dim3(512), 0, stream,
                       y, WyS, ixf, ipre, out);
}

// Round 8
// 162.554 us; speedup vs baseline: 1.8577x; 1.0197x over previous
//
#include <hip/hip_runtime.h>
#include <cstdint>
#include <cstddef>

#define H 512
#define SEQ 128

typedef __bf16 v8bf __attribute__((ext_vector_type(8)));
typedef float v4f __attribute__((ext_vector_type(4)));
typedef unsigned short v8us __attribute__((ext_vector_type(8)));

__device__ __forceinline__ unsigned short f2bf(float f) {
    unsigned int u = __float_as_uint(f);
    u = (u + 0x7FFFu + ((u >> 16) & 1u)) >> 16;
    return (unsigned short)u;
}
__device__ __forceinline__ float bf2f(unsigned short h) {
    return __uint_as_float(((unsigned int)h) << 16);
}
__device__ __forceinline__ v8bf load_bf8(const unsigned short* p) {
    return *reinterpret_cast<const v8bf*>(p);
}
__device__ __forceinline__ float fast_tanh(float v) {
    float e = __expf(2.f * v);
    return 1.f - 2.f * __builtin_amdgcn_rcpf(e + 1.f);
}
__device__ __forceinline__ float fast_sigmoid(float v) {
    return __builtin_amdgcn_rcpf(1.f + __expf(-v));
}
__device__ __forceinline__ v8us cvt8u(float4 lo, float4 hi) {
    v8us r;
    r[0] = f2bf(lo.x); r[1] = f2bf(lo.y); r[2] = f2bf(lo.z); r[3] = f2bf(lo.w);
    r[4] = f2bf(hi.x); r[5] = f2bf(hi.y); r[6] = f2bf(hi.z); r[7] = f2bf(hi.w);
    return r;
}
// async global->LDS, 16B per lane; LDS dest = wave-uniform base + lane*16.
__device__ __forceinline__ void gll16(const unsigned short* g, unsigned short* l) {
    __builtin_amdgcn_global_load_lds(
        (const __attribute__((address_space(1))) unsigned int*)g,
        (__attribute__((address_space(3))) unsigned int*)l, 16, 0, 0);
}

// Swizzled B layout: frag[((c*16 + ks)*64 + lane)*8 + j] = W[g][k]
//   g = c*16 + (lane&15),  k = ks*32 + (lane>>4)*8 + j

// ---------------------------------------------------------------------------
// prep: build swizzled WyS (Wl[:, :512]), WiS (Wl[:, 512:]), WaS (Wa1^T)
// ---------------------------------------------------------------------------
__global__ __launch_bounds__(256) void prep_kernel(
        const float* __restrict__ Wa1, const float* __restrict__ Wl,
        unsigned short* __restrict__ WyS, unsigned short* __restrict__ WiS,
        unsigned short* __restrict__ WaS) {
    int tg = blockIdx.x * 256 + threadIdx.x;   // 0..98303
    int mat = tg >> 15;
    int idx = tg & 32767;
    int lane = idx & 63;
    int ks = (idx >> 6) & 15;
    int c = idx >> 10;
    int g = c * 16 + (lane & 15);
    int hb = ks * 32 + ((lane >> 4) << 3);
    unsigned short o[8];
    unsigned short* dst;
    if (mat == 0) {
        const float* s = Wl + (size_t)g * 1024 + hb;
#pragma unroll
        for (int j = 0; j < 8; ++j) o[j] = f2bf(s[j]);
        dst = WyS + (size_t)idx * 8;
    } else if (mat == 1) {
        const float* s = Wl + (size_t)g * 1024 + 512 + hb;
#pragma unroll
        for (int j = 0; j < 8; ++j) o[j] = f2bf(s[j]);
        dst = WiS + (size_t)idx * 8;
    } else {
#pragma unroll
        for (int j = 0; j < 8; ++j) o[j] = f2bf(Wa1[(size_t)(hb + j) * H + g]);
        dst = WaS + (size_t)idx * 8;
    }
    *reinterpret_cast<ushort4*>(dst)     = *reinterpret_cast<ushort4*>(&o[0]);
    *reinterpret_cast<ushort4*>(dst + 4) = *reinterpret_cast<ushort4*>(&o[4]);
}

// ---------------------------------------------------------------------------
// attn_pool: one block per (b, s<127).  wave = 32 rows x 128 cols, acc 2x8.
// ---------------------------------------------------------------------------
__global__ __launch_bounds__(256, 4) void attn_pool_kernel(
        const float* __restrict__ x, const unsigned short* __restrict__ WaS,
        const float* __restrict__ ba1, const float* __restrict__ wa2,
        float* __restrict__ ixf, unsigned short* __restrict__ ixb) {
    __shared__ __align__(16) unsigned short Xb[32][520];
    __shared__ float attn[32];
    __shared__ float scpart[4][32];

    int bid = blockIdx.x;
    int b = bid / 127, s = bid % 127;
    int t = threadIdx.x;

    const float4* x4 = reinterpret_cast<const float4*>(x + (size_t)(b * SEQ + s) * 32 * H);
#pragma unroll
    for (int i = 0; i < 16; ++i) {
        int idx4 = t + i * 256;
        float4 v = x4[idx4];
        int e = idx4 * 4, m = e >> 9, h = e & 511;
        ushort4 o;
        o.x = f2bf(v.x); o.y = f2bf(v.y); o.z = f2bf(v.z); o.w = f2bf(v.w);
        *reinterpret_cast<ushort4*>(&Xb[m][h]) = o;
    }
    __syncthreads();

    int w = t >> 6, lane = t & 63, q = lane >> 4, c16 = lane & 15;

    v4f acc[2][8];
#pragma unroll
    for (int mi = 0; mi < 2; ++mi)
#pragma unroll
        for (int ci = 0; ci < 8; ++ci) acc[mi][ci] = (v4f){0.f, 0.f, 0.f, 0.f};

    const unsigned short* Bb = WaS + (size_t)(w * 8 * 16) * 512 + lane * 8;

#pragma unroll
    for (int ks = 0; ks < 16; ++ks) {
        v8bf a0 = load_bf8(&Xb[c16][ks * 32 + q * 8]);
        v8bf a1 = load_bf8(&Xb[16 + c16][ks * 32 + q * 8]);
#pragma unroll
        for (int ci = 0; ci < 8; ++ci) {
            v8bf bb = load_bf8(Bb + (size_t)(ci * 16 + ks) * 512);
            acc[0][ci] = __builtin_amdgcn_mfma_f32_16x16x32_bf16(a0, bb, acc[0][ci], 0, 0, 0);
            acc[1][ci] = __builtin_amdgcn_mfma_f32_16x16x32_bf16(a1, bb, acc[1][ci], 0, 0, 0);
        }
    }

    float sr[2][4] = {{0.f, 0.f, 0.f, 0.f}, {0.f, 0.f, 0.f, 0.f}};
#pragma unroll
    for (int ci = 0; ci < 8; ++ci) {
        int g = (w * 8 + ci) * 16 + c16;
        float w2 = wa2[g];
        float bv = ba1[g];
#pragma unroll
        for (int mi = 0; mi < 2; ++mi)
#pragma unroll
            for (int i = 0; i < 4; ++i)
                sr[mi][i] += w2 * fast_tanh(acc[mi][ci][i] + bv);
    }
#pragma unroll
    for (int off = 1; off < 16; off <<= 1) {
#pragma unroll
        for (int mi = 0; mi < 2; ++mi)
#pragma unroll
            for (int i = 0; i < 4; ++i) sr[mi][i] += __shfl_xor(sr[mi][i], off);
    }
    if (c16 == 0) {
#pragma unroll
        for (int mi = 0; mi < 2; ++mi)
#pragma unroll
            for (int i = 0; i < 4; ++i) scpart[w][mi * 16 + q * 4 + i] = sr[mi][i];
    }
    __syncthreads();

    if (t < 64) {
        int m = t & 31;
        float v = scpart[0][m] + scpart[1][m] + scpart[2][m] + scpart[3][m];
        float mx = v;
#pragma unroll
        for (int off = 1; off < 32; off <<= 1) mx = fmaxf(mx, __shfl_xor(mx, off));
        float e = __expf(v - mx);
        float sum = e;
#pragma unroll
        for (int off = 1; off < 32; off <<= 1) sum += __shfl_xor(sum, off);
        if (t < 32) attn[m] = e * __builtin_amdgcn_rcpf(sum);
    }
    __syncthreads();

    int h0 = t * 2;
    float p0 = 0.f, p1 = 0.f;
#pragma unroll
    for (int m = 0; m < 32; ++m) {
        float am = attn[m];
        p0 += am * bf2f(Xb[m][h0]);
        p1 += am * bf2f(Xb[m][h0 + 1]);
    }
    size_t r = (size_t)bid;
    ixf[r * H + h0] = p0;
    ixf[r * H + h0 + 1] = p1;
    ixb[r * H + h0] = f2bf(p0);
    ixb[r * H + h0 + 1] = f2bf(p1);
}

// ---------------------------------------------------------------------------
// ipre: i_pre[r,g] = sum_h i_x[r,h] * Wi[g,h] + bl[g]   (r < 1016)
// ---------------------------------------------------------------------------
__global__ __launch_bounds__(256) void ipre_kernel(
        const unsigned short* __restrict__ ixb, const unsigned short* __restrict__ WiS,
        const float* __restrict__ bl, float* __restrict__ ipre) {
    int row16 = blockIdx.x * 16;
    int t = threadIdx.x, w = t >> 6, lane = t & 63, q = lane >> 4, c16 = lane & 15;
    int c0 = blockIdx.y * 8 + w * 2;

    v4f acc0 = {0.f, 0.f, 0.f, 0.f};
    v4f acc1 = {0.f, 0.f, 0.f, 0.f};
    const unsigned short* arow = ixb + (size_t)(row16 + c16) * H + q * 8;
#pragma unroll
    for (int ks = 0; ks < 16; ++ks) {
        v8bf a = load_bf8(arow + ks * 32);
        acc0 = __builtin_amdgcn_mfma_f32_16x16x32_bf16(
            a, load_bf8(WiS + (size_t)(c0 * 16 + ks) * 512 + lane * 8), acc0, 0, 0, 0);
        acc1 = __builtin_amdgcn_mfma_f32_16x16x32_bf16(
            a, load_bf8(WiS + (size_t)((c0 + 1) * 16 + ks) * 512 + lane * 8), acc1, 0, 0, 0);
    }
#pragma unroll
    for (int cc = 0; cc < 2; ++cc) {
        int g = (c0 + cc) * 16 + c16;
        float blv = bl[g];
        v4f a = cc ? acc1 : acc0;
#pragma unroll
        for (int i = 0; i < 4; ++i) {
            int row = row16 + q * 4 + i;
            if (row < 1016) ipre[(size_t)row * H + g] = a[i] + blv;
        }
    }
}

// ---------------------------------------------------------------------------
// main v8: r7 block-tiled GEMM + (a) B staged via global_load_lds (async,
// no VGPR round-trip -> shorter per-phase dep chain under the 64-arch-VGPR
// cap), (b) bijective XCD swizzle (1016 = 8*127) so the ch=0/1 blocks that
// share A rows land on the same XCD L2.
// Block = 128 rows x 256 cols; 512 thr = 8 waves; wave 32x128, acc[2][8].
// ---------------------------------------------------------------------------
__global__ __launch_bounds__(512, 4) void main_kernel(
        const float* __restrict__ y, const unsigned short* __restrict__ WyS,
        const float* __restrict__ ixf, const float* __restrict__ ipre,
        float* __restrict__ out) {
    int bid0 = blockIdx.x;
    int t = threadIdx.x;

    if (bid0 >= 1016) {
        // s==0 passthrough: 16 blocks, each copies 32 rows x 512 cols f32.
        int cb = bid0 - 1016;            // 0..15
        int b = cb >> 1, half = cb & 1;
        size_t base = ((size_t)(b * SEQ)) * 64 * H + (size_t)half * 32 * H;
        const float4* y4 = reinterpret_cast<const float4*>(y + base);
        float4* o4 = reinterpret_cast<float4*>(out + base);
#pragma unroll
        for (int i = 0; i < 8; ++i) o4[t + i * 512] = y4[t + i * 512];
        return;
    }

    // XCD-aware bijective swizzle: 1016 = 8 XCDs * 127 contiguous blocks.
    int bid = (bid0 & 7) * 127 + (bid0 >> 3);

    int rg = bid >> 1;                   // row-group: 128 rows = tiles 2rg, 2rg+1
    int ch = bid & 1;                    // col half: g in [ch*256, ch*256+256)

    __shared__ __align__(16) unsigned short Ab[2][128 * 40];   // 40 = 32 + 8 pad
    __shared__ __align__(16) unsigned short Bb[2][16 * 512];
    __shared__ float ip_s[2][256];
    __shared__ float ix_s[2][256];

    int t0 = rg * 2;

    // ---- per-thread A staging assignment (fixed row, 8 f32 per phase) ----
    int arow  = t >> 2;                  // 0..127
    int acol0 = (t & 3) * 8;             // 0,8,16,24
    int atid  = t0 + (arow >> 6);
    int ab    = atid / 127, asm1 = atid % 127;
    const float* yrow = y + ((size_t)(ab * SEQ + asm1 + 1) * 64 + (arow & 63)) * H;

    // ---- per-thread B staging assignment (2 chunks of 16B per phase) ----
    int w = t >> 6, lane = t & 63, q = lane >> 4, c16 = lane & 15;
    int ck0 = w * 2;                     // chunks ck0, ck0+1 (0..15), wave-uniform
    const unsigned short* bsrc0 = WyS + (size_t)((ch * 16 + ck0) * 16) * 512 + lane * 8;
    const unsigned short* bsrc1 = WyS + (size_t)((ch * 16 + ck0 + 1) * 16) * 512 + lane * 8;

    // ---- ip/ix staging (once) ----
    {
        int tile = t >> 8, gl = t & 255;
        size_t rrow = (size_t)(t0 + tile) * H + ch * 256 + gl;
        ip_s[tile][gl] = ipre[rrow];
        ix_s[tile][gl] = ixf[rrow];
    }

    // ---- prologue: stage phase 0 ----
    {
        gll16(bsrc0, &Bb[0][ck0 * 512]);          // dest: base + lane*16
        gll16(bsrc1, &Bb[0][(ck0 + 1) * 512]);
        float4 a0 = *reinterpret_cast<const float4*>(yrow + acol0);
        float4 a1 = *reinterpret_cast<const float4*>(yrow + acol0 + 4);
        *reinterpret_cast<v8us*>(&Ab[0][arow * 40 + acol0]) = cvt8u(a0, a1);
    }
    __syncthreads();

    int wr = w >> 1;                     // 0..3  row-group within block
    int wc = w & 1;                      // 0..1  col-half within block's 256

    v4f acc[2][8];
#pragma unroll
    for (int rt = 0; rt < 2; ++rt)
#pragma unroll
        for (int ci = 0; ci < 8; ++ci) acc[rt][ci] = (v4f){0.f, 0.f, 0.f, 0.f};

    // ---- main K loop: 16 phases, dbuf, async B, issue-early / write-late ----
#pragma unroll
    for (int p = 0; p < 16; ++p) {
        const int cur = p & 1;
        float4 na0, na1;
        if (p < 15) {
            // async B for p+1 straight into the other LDS buffer
            gll16(bsrc0 + (p + 1) * 512, &Bb[cur ^ 1][ck0 * 512]);
            gll16(bsrc1 + (p + 1) * 512, &Bb[cur ^ 1][(ck0 + 1) * 512]);
            // A for p+1 into registers (needs f32->bf16 convert)
            na0 = *reinterpret_cast<const float4*>(yrow + (p + 1) * 32 + acol0);
            na1 = *reinterpret_cast<const float4*>(yrow + (p + 1) * 32 + acol0 + 4);
        }

        v8bf af0 = load_bf8(&Ab[cur][(wr * 32 + c16) * 40 + q * 8]);
        v8bf af1 = load_bf8(&Ab[cur][(wr * 32 + 16 + c16) * 40 + q * 8]);
#pragma unroll
        for (int ci = 0; ci < 8; ++ci) {
            v8bf bf = load_bf8(&Bb[cur][(wc * 8 + ci) * 512 + lane * 8]);
            acc[0][ci] = __builtin_amdgcn_mfma_f32_16x16x32_bf16(af0, bf, acc[0][ci], 0, 0, 0);
            acc[1][ci] = __builtin_amdgcn_mfma_f32_16x16x32_bf16(af1, bf, acc[1][ci], 0, 0, 0);
        }

        if (p < 15) {
            *reinterpret_cast<v8us*>(&Ab[cur ^ 1][arow * 40 + acol0]) = cvt8u(na0, na1);
            __syncthreads();   // drains vmcnt (async B) + lgkmcnt (A writes)
        }
    }

    // ---- epilogue: out = y + ix * sigmoid(acc + ip), f32 residual ----
    int tb0 = t0, tb1 = t0 + 1;
    size_t obase0 = ((size_t)((tb0 / 127) * SEQ + tb0 % 127 + 1) * 64) * H;
    size_t obase1 = ((size_t)((tb1 / 127) * SEQ + tb1 % 127 + 1) * 64) * H;
    int tile = wr >> 1;                  // wave-uniform: rows 0..63 -> tile 0
    size_t obase = tile ? obase1 : obase0;

#pragma unroll
    for (int ci = 0; ci < 8; ++ci) {
        int gl = (wc * 8 + ci) * 16 + c16;       // 0..255
        int g = ch * 256 + gl;
        float ip = ip_s[tile][gl];
        float ixv = ix_s[tile][gl];
#pragma unroll
        for (int rt = 0; rt < 2; ++rt) {
#pragma unroll
            for (int i = 0; i < 4; ++i) {
                int n = ((wr & 1) * 32) + rt * 16 + q * 4 + i;   // row within tile
                size_t off = obase + (size_t)n * H + g;
                float yv = y[off];
                float pre = acc[rt][ci][i] + ip;
                out[off] = yv + ixv * fast_sigmoid(pre);
            }
        }
    }
}

// ---------------------------------------------------------------------------
extern "C" void kernel_launch(void* const* d_in, const int* in_sizes, int n_in,
                              void* d_out, int out_size, void* d_ws, size_t ws_size,
                              hipStream_t stream) {
    const float* x   = (const float*)d_in[0];
    const float* y   = (const float*)d_in[1];
    const float* Wa1 = (const float*)d_in[2];
    const float* ba1 = (const float*)d_in[3];
    const float* wa2 = (const float*)d_in[4];
    const float* Wl  = (const float*)d_in[5];
    const float* bl  = (const float*)d_in[6];
    float* out = (float*)d_out;

    char* ws = (char*)d_ws;
    unsigned short* WyS  = (unsigned short*)(ws);                     // 512 KB
    unsigned short* WiS  = (unsigned short*)(ws + 524288);            // 512 KB
    unsigned short* WaS  = (unsigned short*)(ws + 1048576);           // 512 KB
    float*          ixf  = (float*)(ws + 1572864);                    // 2 MB (1024 rows)
    unsigned short* ixb  = (unsigned short*)(ws + 3670016);           // 1 MB (1024 rows)
    float*          ipre = (float*)(ws + 4718592);                    // 2 MB (1024 rows)

    hipLaunchKernelGGL(prep_kernel, dim3(384), dim3(256), 0, stream, Wa1, Wl, WyS, WiS, WaS);
    hipLaunchKernelGGL(attn_pool_kernel, dim3(1016), dim3(256), 0, stream,
                       x, WaS, ba1, wa2, ixf, ixb);
    hipLaunchKernelGGL(ipre_kernel, dim3(64, 4), dim3(256), 0, stream, ixb, WiS, bl, ipre);
    hipLaunchKernelGGL(main_kernel, dim3(1032), dim3(512), 0, stream,
                       y, WyS, ixf, ipre, out);
}